// Round 2
// baseline (210.054 us; speedup 1.0000x reference)
//
#include <hip/hip_runtime.h>

// Cholesky-from-partial-correlations.
// Closed form per (batch b, row i):
//   out[b,i,j] = z_j * sqrt( prod_{k<j} (1 - z_k^2) )   for j < i
//   out[b,i,i] = 1,  out[b,i,j>i] = 0
// One 64-lane wave per row; exclusive prefix product via shfl scan.

#define SIZE 256
#define BATCH 512
#define M (SIZE * (SIZE - 1) / 2)   // 32640

__global__ __launch_bounds__(256) void chol_from_z_kernel(
    const float* __restrict__ vec, float* __restrict__ out) {
    const int lane = threadIdx.x & 63;
    const int wave = (blockIdx.x * blockDim.x + threadIdx.x) >> 6;  // 0 .. BATCH*SIZE-1
    const int b = wave >> 8;      // batch index
    const int i = wave & 255;     // row index

    const size_t row_off = (size_t)b * M + ((size_t)i * (size_t)(i - 1)) / 2;
    const float* __restrict__ s = vec + row_off;
    float* __restrict__ dst = out + (((size_t)b * SIZE) + i) * SIZE;

    const int L = i;          // number of strictly-lower entries in this row
    float carry = 1.0f;       // product of (1 - z^2) over all previous chunks

    #pragma unroll
    for (int c = 0; c < 4; ++c) {
        const int j = c * 64 + lane;
        if (c * 64 > i) {
            // whole chunk strictly above diagonal: zeros only (wave-uniform branch)
            dst[j] = 0.0f;
            continue;
        }
        float z = 0.0f;
        if (j < L) z = s[j];
        float t = 1.0f - z * z;          // inactive lanes contribute 1 (identity)

        // inclusive prefix product across the wave
        float p = t;
        #pragma unroll
        for (int d = 1; d < 64; d <<= 1) {
            float v = __shfl_up(p, d, 64);
            if (lane >= d) p *= v;
        }
        // exclusive prefix
        float excl = __shfl_up(p, 1, 64);
        if (lane == 0) excl = 1.0f;
        const float P = carry * excl;

        float x;
        if (j < L)       x = z * sqrtf(P);   // sign carried by z
        else if (j == i) x = 1.0f;
        else             x = 0.0f;
        dst[j] = x;

        carry *= __shfl(p, 63, 64);
    }
}

extern "C" void kernel_launch(void* const* d_in, const int* in_sizes, int n_in,
                              void* d_out, int out_size, void* d_ws, size_t ws_size,
                              hipStream_t stream) {
    const float* vec = (const float*)d_in[0];
    float* out = (float*)d_out;
    // BATCH*SIZE waves, 4 waves (256 threads) per block
    const int n_waves = BATCH * SIZE;           // 131072
    const int blocks = n_waves / 4;             // 32768
    chol_from_z_kernel<<<blocks, 256, 0, stream>>>(vec, out);
}

// Round 3
// 183.047 us; speedup vs baseline: 1.1475x; 1.1475x over previous
//
#include <hip/hip_runtime.h>

// Cholesky-from-partial-correlations.
// Closed form per (batch b, row i):
//   out[b,i,j] = z_j * sqrt( prod_{k<j} (1 - z_k^2) )   for j < i
//   out[b,i,i] = 1,  out[b,i,j>i] = 0
// One 64-lane wave per row. Each lane owns 4 CONSECUTIVE elements:
// local serial product -> ONE wave scan (6 shuffles) -> serial emit.
// float4 store (dst rows are 1 KiB aligned).

#define SIZE 256
#define BATCH 512
#define M (SIZE * (SIZE - 1) / 2)   // 32640

__global__ __launch_bounds__(256) void chol_from_z_kernel(
    const float* __restrict__ vec, float* __restrict__ out) {
    const int lane = threadIdx.x & 63;
    const int wave = (blockIdx.x * blockDim.x + threadIdx.x) >> 6;  // 0 .. BATCH*SIZE-1
    const int b = wave >> 8;      // batch index
    const int i = wave & 255;     // row index

    const size_t row_off = (size_t)b * M + ((size_t)i * (size_t)(i - 1)) / 2;
    const float* __restrict__ s = vec + row_off;
    float* __restrict__ dst = out + (((size_t)b << 8) + (size_t)i) * SIZE;

    const int L = i;              // number of strictly-lower entries in this row
    const int j0 = lane << 2;     // this lane's first element index

    // independent predicated loads (z=0 outside the row -> t=1, identity)
    float z0 = 0.f, z1 = 0.f, z2 = 0.f, z3 = 0.f;
    if (j0     < L) z0 = s[j0];
    if (j0 + 1 < L) z1 = s[j0 + 1];
    if (j0 + 2 < L) z2 = s[j0 + 2];
    if (j0 + 3 < L) z3 = s[j0 + 3];

    const float t0 = 1.f - z0 * z0;
    const float t1 = 1.f - z1 * z1;
    const float t2 = 1.f - z2 * z2;
    const float t3 = 1.f - z3 * z3;
    float local = t0 * t1 * t2 * t3;

    // single inclusive prefix product across the wave
    float p = local;
    #pragma unroll
    for (int d = 1; d < 64; d <<= 1) {
        float v = __shfl_up(p, d, 64);
        if (lane >= d) p *= v;
    }
    // exclusive prefix = carry entering this lane's segment
    float run = __shfl_up(p, 1, 64);
    if (lane == 0) run = 1.f;

    float4 o;
    o.x = (j0     < L) ? z0 * sqrtf(run) : ((j0     == i) ? 1.f : 0.f); run *= t0;
    o.y = (j0 + 1 < L) ? z1 * sqrtf(run) : ((j0 + 1 == i) ? 1.f : 0.f); run *= t1;
    o.z = (j0 + 2 < L) ? z2 * sqrtf(run) : ((j0 + 2 == i) ? 1.f : 0.f); run *= t2;
    o.w = (j0 + 3 < L) ? z3 * sqrtf(run) : ((j0 + 3 == i) ? 1.f : 0.f);

    *(float4*)(dst + j0) = o;   // dst is 1 KiB-aligned per row; j0 is 16B-aligned
}

extern "C" void kernel_launch(void* const* d_in, const int* in_sizes, int n_in,
                              void* d_out, int out_size, void* d_ws, size_t ws_size,
                              hipStream_t stream) {
    const float* vec = (const float*)d_in[0];
    float* out = (float*)d_out;
    const int n_waves = BATCH * SIZE;           // 131072 rows
    const int blocks = n_waves / 4;             // 4 waves (256 thr) per block
    chol_from_z_kernel<<<blocks, 256, 0, stream>>>(vec, out);
}